// Round 7
// baseline (422.310 us; speedup 1.0000x reference)
//
#include <hip/hip_runtime.h>
#include <hip/hip_bf16.h>
#include <math.h>

// ---------------------------------------------------------------------------
// GCN forward. bf16 MFMA GEMMs, gather aggregation on bf16 payload,
// 2-pass binned CSR build (part-sorted then placed, XCD-affine windows).
//   S(bf16) = X@W1 (MFMA) ; Bh(bf16) = relu(agg(S)+b1) ;
//   S(bf16) = Bh@W2 (MFMA) ; rep(f32) = relu(agg(S)+b2) -> d_out
//   (+ fused e = sigmoid(rep@pw+pb)) ; tau via register-blocked GEMM.
// ---------------------------------------------------------------------------

#define SCAN_CHUNK 1024   // elements per scan block (256 thr x 4)
#define NPART 8           // dst-range partitions (~XCDs)
#define BIN_CH 4096       // edges per k_bin block
#define PLACE_BPP 64      // k_place blocks per partition

typedef __attribute__((ext_vector_type(8))) short bfrag;   // 8 bf16 (4 VGPR)
typedef __attribute__((ext_vector_type(4))) float ffrag;   // 4 f32 acc

static __device__ __forceinline__ ushort f2bf(float f) {
    __hip_bfloat16 h = __float2bfloat16(f);
    return *reinterpret_cast<ushort*>(&h);
}
static __device__ __forceinline__ float bf2f(ushort u) {
    __hip_bfloat16 h;
    *reinterpret_cast<ushort*>(&h) = u;
    return __bfloat162float(h);
}

// ---------------- CSR build ----------------

__global__ __launch_bounds__(256) void k_hist(const int* __restrict__ dst,
                                              int* __restrict__ cnt, int nE) {
    int e = blockIdx.x * 256 + threadIdx.x;
    if (e < nE) atomicAdd(&cnt[dst[e]], 1);
}

__global__ __launch_bounds__(256) void k_blocksum(const int* __restrict__ cnt,
                                                  int* __restrict__ bsum, int nN) {
    __shared__ int s[256];
    const int b = blockIdx.x, t = threadIdx.x;
    const int base = b * SCAN_CHUNK + t * 4;
    int v = 0;
    #pragma unroll
    for (int j = 0; j < 4; ++j) { int i = base + j; if (i < nN) v += cnt[i]; }
    s[t] = v; __syncthreads();
    for (int o = 128; o; o >>= 1) { if (t < o) s[t] += s[t + o]; __syncthreads(); }
    if (t == 0) bsum[b] = s[0];
}

__global__ void k_scanb(int* __restrict__ bsum, int nb) {   // 1 block, 128 thr
    __shared__ int s[128];
    const int t = threadIdx.x;
    const int v = (t < nb) ? bsum[t] : 0;
    s[t] = v; __syncthreads();
    for (int o = 1; o < 128; o <<= 1) {
        int u = (t >= o) ? s[t - o] : 0;
        __syncthreads(); s[t] += u; __syncthreads();
    }
    if (t < nb) bsum[t] = s[t] - v;   // exclusive
}

// writes exclusive offsets off[], zeroes cnt[] for reuse as fill cursor
__global__ __launch_bounds__(256) void k_writeoff(int* __restrict__ cnt,
                                                  int* __restrict__ off,
                                                  const int* __restrict__ bsum,
                                                  int nN, int nE) {
    __shared__ int s[256];
    const int b = blockIdx.x, t = threadIdx.x;
    const int base = b * SCAN_CHUNK + t * 4;
    int c[4]; int sum = 0;
    #pragma unroll
    for (int j = 0; j < 4; ++j) { int i = base + j; c[j] = (i < nN) ? cnt[i] : 0; sum += c[j]; }
    s[t] = sum; __syncthreads();
    int v = sum;
    for (int o = 1; o < 256; o <<= 1) {
        int u = (t >= o) ? s[t - o] : 0;
        __syncthreads(); s[t] += u; __syncthreads();
    }
    int run = s[t] - v + bsum[b];     // exclusive within grid
    #pragma unroll
    for (int j = 0; j < 4; ++j) {
        int i = base + j;
        if (i < nN) { off[i] = run; run += c[j]; cnt[i] = 0; }
    }
    if (b == 0 && t == 0) off[nN] = nE;
}

__global__ void k_initcur(const int* __restrict__ off, int* __restrict__ gcur,
                          int nN, int psz) {
    int p = threadIdx.x;
    if (p < NPART) { int lo = p * psz; if (lo > nN) lo = nN; gcur[p] = off[lo]; }
}

// Pass 1: bin edges by dst-partition. Per block: LDS histogram over its chunk,
// one global reservation per part, then dense per-(block,part) runs written.
__global__ __launch_bounds__(256) void k_bin(const int* __restrict__ edst,
                                             const int* __restrict__ esrc,
                                             const float* __restrict__ ew,
                                             int* __restrict__ gcur,
                                             unsigned int* __restrict__ pkbin,
                                             unsigned short* __restrict__ dlbin,
                                             int nE, int psz) {
    __shared__ int hcnt[NPART], hbase[NPART], hcur[NPART];
    const int tid = threadIdx.x;
    const int e0  = blockIdx.x * BIN_CH;

    if (tid < NPART) hcnt[tid] = 0;
    __syncthreads();
    for (int i = tid; i < BIN_CH; i += 256) {
        int e = e0 + i;
        if (e < nE) atomicAdd(&hcnt[edst[e] / psz], 1);
    }
    __syncthreads();
    if (tid < NPART) { hbase[tid] = atomicAdd(&gcur[tid], hcnt[tid]); hcur[tid] = 0; }
    __syncthreads();
    for (int i = tid; i < BIN_CH; i += 256) {
        int e = e0 + i;
        if (e < nE) {
            int d = edst[e];
            int p = d / psz;
            int pos = atomicAdd(&hcur[p], 1);
            int idx = hbase[p] + pos;
            unsigned int w15 = (unsigned int)rintf(ew[e] * 32767.0f);
            pkbin[idx] = (w15 << 17) | (unsigned int)esrc[e];
            dlbin[idx] = (unsigned short)(d - p * psz);
        }
    }
}

// Pass 2: per-part placement. Reads its part's contiguous pkbin/dlbin slice
// (coalesced), writes spack within the part's ~0.8 MB window (part=blockIdx&7
// -> XCD-affine). cnt[] was zeroed by k_writeoff, used as per-dst cursor.
__global__ __launch_bounds__(256) void k_place(const unsigned int* __restrict__ pkbin,
                                               const unsigned short* __restrict__ dlbin,
                                               const int* __restrict__ off,
                                               int* __restrict__ cnt,
                                               unsigned int* __restrict__ spack,
                                               int nN, int psz) {
    const int part = blockIdx.x & (NPART - 1);
    const int bi   = blockIdx.x >> 3;
    int lo = part * psz; if (lo > nN) lo = nN;
    int hi = lo + psz;   if (hi > nN) hi = nN;
    const int base  = off[lo];
    const int tot   = off[hi] - base;
    const int chunk = (tot + PLACE_BPP - 1) / PLACE_BPP;
    const int s  = bi * chunk;
    int en = s + chunk; if (en > tot) en = tot;
    for (int i = s + (int)threadIdx.x; i < en; i += 256) {
        unsigned int pk = pkbin[base + i];
        int d = lo + (int)dlbin[base + i];
        int r = atomicAdd(&cnt[d], 1);
        spack[off[d] + r] = pk;
    }
}

// ---------------- weight prep: Wt[n][k] = bf16(W[k][n]) ----------------
__global__ __launch_bounds__(256) void k_prepW(const float* __restrict__ W1,
                                               const float* __restrict__ W2,
                                               ushort* __restrict__ Wt1,
                                               ushort* __restrict__ Wt2) {
    const float* W  = (blockIdx.x == 0) ? W1 : W2;
    ushort*      Wt = (blockIdx.x == 0) ? Wt1 : Wt2;
    for (int j = 0; j < 64; ++j) {
        int idx = threadIdx.x + j * 256;    // 0..16383, coalesced read
        int k = idx >> 7, n = idx & 127;
        Wt[n * 128 + k] = f2bf(W[idx]);
    }
}

// ---------------- MFMA GEMM: Y[n,128](bf16) = A[n,128] @ W[128,128] ----------
// 64 rows/block, 4 waves (16 rows each x 128 cols), K=128 in 4 steps of 32.
// A staged to LDS as bf16 with XOR swizzle (byte ^= (row&7)<<4).
// B read from pre-transposed global Wt[n][k] (32 KB, L1/L2-hot).
template <int ABF16>
__global__ __launch_bounds__(256) void gemm_mfma(
    const void* __restrict__ Av, const ushort* __restrict__ Wt,
    ushort* __restrict__ Y, int nN)
{
    __shared__ ushort Xl[64 * 128];   // 16 KB, swizzled
    const int tid  = threadIdx.x;
    const int row0 = blockIdx.x * 64;

    if (ABF16) {
        const int4* X16 = (const int4*)Av;          // bf16 rows, 16 int4 each
        #pragma unroll
        for (int j = 0; j < 4; ++j) {
            int u  = tid + j * 256;                 // 0..1023
            int r  = u >> 4;
            int cb = (u & 15) * 16;                 // byte offset in row
            int grow = row0 + r;
            int4 v = make_int4(0, 0, 0, 0);
            if (grow < nN) v = X16[(size_t)grow * 16 + (u & 15)];
            *(int4*)((char*)Xl + r * 256 + (cb ^ ((r & 7) << 4))) = v;
        }
    } else {
        const float4* X4 = (const float4*)Av;       // f32 rows, 32 float4 each
        #pragma unroll
        for (int j = 0; j < 8; ++j) {
            int u  = tid + j * 256;                 // 0..2047
            int r  = u >> 5;
            int c4 = (u & 31) * 4;                  // element col
            int grow = row0 + r;
            float4 v = make_float4(0.f, 0.f, 0.f, 0.f);
            if (grow < nN) v = X4[(size_t)grow * 32 + (u & 31)];
            ushort4 o;
            o.x = f2bf(v.x); o.y = f2bf(v.y); o.z = f2bf(v.z); o.w = f2bf(v.w);
            *(ushort4*)((char*)Xl + r * 256 + ((c4 * 2) ^ ((r & 7) << 4))) = o;
        }
    }
    __syncthreads();

    const int lane = tid & 63;
    const int wid  = tid >> 6;
    const int wrow = wid * 16;                      // wave's local row base
    const int arow = wrow + (lane & 15);
    const int kg16 = (lane >> 4) * 16;              // k-group byte offset

    ffrag acc[8];
    #pragma unroll
    for (int ct = 0; ct < 8; ++ct) acc[ct] = (ffrag){0.f, 0.f, 0.f, 0.f};

    #pragma unroll
    for (int ks = 0; ks < 4; ++ks) {
        const int abyte = arow * 256 + ((ks * 64 + kg16) ^ ((arow & 7) << 4));
        bfrag a = *(const bfrag*)((const char*)Xl + abyte);
        #pragma unroll
        for (int ct = 0; ct < 8; ++ct) {
            const int wcol = ct * 16 + (lane & 15);
            bfrag b = *(const bfrag*)(Wt + wcol * 128 + ks * 32 + (lane >> 4) * 8);
            acc[ct] = __builtin_amdgcn_mfma_f32_16x16x32_bf16(a, b, acc[ct], 0, 0, 0);
        }
    }

    // D layout (verified m89): col = lane&15, row = (lane>>4)*4 + i
    #pragma unroll
    for (int ct = 0; ct < 8; ++ct) {
        #pragma unroll
        for (int i = 0; i < 4; ++i) {
            int row = row0 + wrow + (lane >> 4) * 4 + i;
            if (row < nN)
                Y[(size_t)row * 128 + ct * 16 + (lane & 15)] = f2bf(acc[ct][i]);
        }
    }
}

// ---------------- gather aggregation (bf16 payload, fp32 accum) -------------
// out[n] = relu( sum_j S[src_j]*w_j + bias ), 32 lanes / node, unroll 8.
// OUTBF: write bf16 (feeds MFMA GEMM2). EP: fused e = sigmoid(rep.pw+pb).
template <int EP, int OUTBF>
__global__ __launch_bounds__(256) void k_aggregate(
    const ushort* __restrict__ S, const unsigned int* __restrict__ spack,
    const int* __restrict__ off, const float* __restrict__ bias,
    void* __restrict__ out, const float* __restrict__ pw,
    const float* __restrict__ pb, float* __restrict__ out_e, int nN)
{
    const int g    = (blockIdx.x * 256 + threadIdx.x) >> 5;   // node id
    const int lane = threadIdx.x & 31;
    if (g >= nN) return;
    const int c  = lane * 4;
    const int j0 = off[g], j1 = off[g + 1];

    float4 acc = make_float4(0.f, 0.f, 0.f, 0.f);
    const float wscale = 1.0f / 32767.0f;

    int j = j0;
    for (; j + 8 <= j1; j += 8) {
        unsigned int p[8];
        #pragma unroll
        for (int q = 0; q < 8; ++q) p[q] = spack[j + q];
        ushort4 v[8];
        #pragma unroll
        for (int q = 0; q < 8; ++q)
            v[q] = *(const ushort4*)&S[(size_t)(p[q] & 0x1FFFF) * 128 + c];
        #pragma unroll
        for (int q = 0; q < 8; ++q) {
            const float w = (float)(p[q] >> 17) * wscale;
            acc.x = fmaf(bf2f(v[q].x), w, acc.x);
            acc.y = fmaf(bf2f(v[q].y), w, acc.y);
            acc.z = fmaf(bf2f(v[q].z), w, acc.z);
            acc.w = fmaf(bf2f(v[q].w), w, acc.w);
        }
    }
    for (; j < j1; ++j) {
        const unsigned int p = spack[j];
        const float w = (float)(p >> 17) * wscale;
        const ushort4 v = *(const ushort4*)&S[(size_t)(p & 0x1FFFF) * 128 + c];
        acc.x = fmaf(bf2f(v.x), w, acc.x);
        acc.y = fmaf(bf2f(v.y), w, acc.y);
        acc.z = fmaf(bf2f(v.z), w, acc.z);
        acc.w = fmaf(bf2f(v.w), w, acc.w);
    }

    const float4 bb = ((const float4*)bias)[lane];
    acc.x = fmaxf(acc.x + bb.x, 0.f);
    acc.y = fmaxf(acc.y + bb.y, 0.f);
    acc.z = fmaxf(acc.z + bb.z, 0.f);
    acc.w = fmaxf(acc.w + bb.w, 0.f);

    if (OUTBF) {
        ushort4 o;
        o.x = f2bf(acc.x); o.y = f2bf(acc.y); o.z = f2bf(acc.z); o.w = f2bf(acc.w);
        *(ushort4*)&((ushort*)out)[(size_t)g * 128 + c] = o;
    } else {
        *(float4*)&((float*)out)[(size_t)g * 128 + c] = acc;
    }

    if (EP) {
        const float4 pv = ((const float4*)pw)[lane];
        float ep = acc.x * pv.x + acc.y * pv.y + acc.z * pv.z + acc.w * pv.w;
        #pragma unroll
        for (int o = 1; o < 32; o <<= 1) ep += __shfl_xor(ep, o);
        if (lane == 0) out_e[g] = 1.f / (1.f + expf(-(ep + pb[0])));
    }
}

// ---------------- tau head: register-blocked GEMM ----------------
__global__ __launch_bounds__(256) void tau_kernel(
    const float* __restrict__ REP, const float* __restrict__ tw1,
    const float* __restrict__ tb1, const float* __restrict__ tw2,
    const float* __restrict__ tb2, float* __restrict__ out_tau, int nN)
{
    __shared__ float Rl[64 * 132];    // 33.8 KB, padded
    __shared__ float Wl[64 * 64];     // 16 KB, one k-chunk of tw1
    __shared__ float stb1[64], stw2[64];

    const int tid  = threadIdx.x;
    const int row0 = blockIdx.x * 64;

    if (tid < 64) { stb1[tid] = tb1[tid]; stw2[tid] = tw2[tid]; }

    #pragma unroll
    for (int j = 0; j < 8; ++j) {
        int i  = tid + j * 256;
        int r  = i >> 5;
        int c4 = i & 31;
        float4 v = make_float4(0.f, 0.f, 0.f, 0.f);
        if (row0 + r < nN) v = ((const float4*)REP)[(size_t)(row0 + r) * 32 + c4];
        ((float4*)Rl)[r * 33 + c4] = v;
    }

    const int cg = tid & 15;    // cols cg*4..+3
    const int rt = tid >> 4;    // rows rt*4..+3

    float4 acc[4];
    #pragma unroll
    for (int r = 0; r < 4; ++r) acc[r] = make_float4(0.f, 0.f, 0.f, 0.f);

    for (int kc = 0; kc < 2; ++kc) {
        __syncthreads();
        {
            const float4* s4 = (const float4*)tw1 + kc * 1024;
            #pragma unroll
            for (int j = 0; j < 4; ++j)
                ((float4*)Wl)[tid + j * 256] = s4[tid + j * 256];
        }
        __syncthreads();
        #pragma unroll
        for (int k4 = 0; k4 < 16; ++k4) {
            float4 xr[4];
            #pragma unroll
            for (int r = 0; r < 4; ++r)
                xr[r] = *(const float4*)&Rl[(rt * 4 + r) * 132 + kc * 64 + k4 * 4];
            #pragma unroll
            for (int kk = 0; kk < 4; ++kk) {
                float4 w = *(const float4*)&Wl[(k4 * 4 + kk) * 64 + cg * 4];
                #pragma unroll
                for (int r = 0; r < 4; ++r) {
                    float xv = (kk == 0) ? xr[r].x : (kk == 1) ? xr[r].y
                             : (kk == 2) ? xr[r].z : xr[r].w;
                    acc[r].x = fmaf(xv, w.x, acc[r].x);
                    acc[r].y = fmaf(xv, w.y, acc[r].y);
                    acc[r].z = fmaf(xv, w.z, acc[r].z);
                    acc[r].w = fmaf(xv, w.w, acc[r].w);
                }
            }
        }
    }

    const float4 tb = *(const float4*)&stb1[cg * 4];
    const float4 t2 = *(const float4*)&stw2[cg * 4];
    float taup[4];
    #pragma unroll
    for (int r = 0; r < 4; ++r) {
        float hx = fmaxf(acc[r].x + tb.x, 0.f);
        float hy = fmaxf(acc[r].y + tb.y, 0.f);
        float hz = fmaxf(acc[r].z + tb.z, 0.f);
        float hw = fmaxf(acc[r].w + tb.w, 0.f);
        taup[r] = hx * t2.x + hy * t2.y + hz * t2.z + hw * t2.w;
    }
    #pragma unroll
    for (int o = 1; o < 16; o <<= 1) {
        #pragma unroll
        for (int r = 0; r < 4; ++r) taup[r] += __shfl_xor(taup[r], o);
    }
    if (cg == 0) {
        const float tb2v = tb2[0];
        #pragma unroll
        for (int r = 0; r < 4; ++r) {
            int row = row0 + rt * 4 + r;
            if (row < nN) out_tau[row] = taup[r] + tb2v;
        }
    }
}

// ---------------- launch ----------------
extern "C" void kernel_launch(void* const* d_in, const int* in_sizes, int n_in,
                              void* d_out, int out_size, void* d_ws, size_t ws_size,
                              hipStream_t stream)
{
    const float* x   = (const float*)d_in[0];
    const float* ew  = (const float*)d_in[1];
    const float* W1  = (const float*)d_in[2];
    const float* b1  = (const float*)d_in[3];
    const float* W2  = (const float*)d_in[4];
    const float* b2  = (const float*)d_in[5];
    const float* tw1 = (const float*)d_in[6];
    const float* tb1 = (const float*)d_in[7];
    const float* tw2 = (const float*)d_in[8];
    const float* tb2 = (const float*)d_in[9];
    const float* pw  = (const float*)d_in[10];
    const float* pb  = (const float*)d_in[11];
    const int* esrc  = (const int*)d_in[12];
    const int* edst  = (const int*)d_in[13];

    const int nN = in_sizes[0] / 128;   // 100000
    const int nE = in_sizes[1];         // 1600000

    // workspace carve-up (all big arrays 16B-aligned)
    char* w = (char*)d_ws;
    ushort*         S     = (ushort*)w;          w += (size_t)nN * 128 * 2;  // bf16 support
    ushort*         Bh    = (ushort*)w;          w += (size_t)nN * 128 * 2;  // bf16 hidden
    unsigned int*   spack = (unsigned int*)w;    w += (size_t)nE * 4;        // dst-sorted packs
    unsigned int*   pkbin = (unsigned int*)w;    w += (size_t)nE * 4;        // part-sorted packs
    unsigned short* dlbin = (unsigned short*)w;  w += (size_t)nE * 2;        // part-sorted dstLocal
    ushort*         Wt1   = (ushort*)w;          w += 16384 * 2;             // W1^T bf16
    ushort*         Wt2   = (ushort*)w;          w += 16384 * 2;             // W2^T bf16
    int*            cnt   = (int*)w;             w += (size_t)nN * 4;
    int*            off   = (int*)w;             w += (size_t)(nN + 1) * 4;
    int*            bsum  = (int*)w;             w += 128 * 4;
    int*            gcur  = (int*)w;             w += 64;

    float* out_tau = (float*)d_out;
    float* out_e   = out_tau + nN;
    float* out_rep = out_e + nN;

    const int nb         = (nN + SCAN_CHUNK - 1) / SCAN_CHUNK;   // 98
    const int edgeBlocks = (nE + 255) / 256;
    const int binBlocks  = (nE + BIN_CH - 1) / BIN_CH;
    const int gemmBlocks = (nN + 63) / 64;
    const int aggBlocks  = (nN + 7) / 8;
    const int tauBlocks  = (nN + 63) / 64;
    const int psz        = (nN + NPART - 1) / NPART;             // 12500

    // ---- CSR build (by dst), 2-pass binned ----
    hipMemsetAsync(cnt, 0, (size_t)nN * sizeof(int), stream);
    k_hist<<<edgeBlocks, 256, 0, stream>>>(edst, cnt, nE);
    k_blocksum<<<nb, 256, 0, stream>>>(cnt, bsum, nN);
    k_scanb<<<1, 128, 0, stream>>>(bsum, nb);
    k_writeoff<<<nb, 256, 0, stream>>>(cnt, off, bsum, nN, nE);
    k_initcur<<<1, 64, 0, stream>>>(off, gcur, nN, psz);
    k_bin<<<binBlocks, 256, 0, stream>>>(edst, esrc, ew, gcur, pkbin, dlbin, nE, psz);
    k_place<<<NPART * PLACE_BPP, 256, 0, stream>>>(pkbin, dlbin, off, cnt, spack, nN, psz);

    // ---- weight transpose+cast ----
    k_prepW<<<2, 256, 0, stream>>>(W1, W2, Wt1, Wt2);

    // ---- layer 1 ----
    gemm_mfma<0><<<gemmBlocks, 256, 0, stream>>>(x, Wt1, S, nN);
    k_aggregate<0, 1><<<aggBlocks, 256, 0, stream>>>(S, spack, off, b1, Bh,
                                                     nullptr, nullptr, nullptr, nN);

    // ---- layer 2 (rep -> d_out, e fused) ----
    gemm_mfma<1><<<gemmBlocks, 256, 0, stream>>>(Bh, Wt2, S, nN);
    k_aggregate<1, 0><<<aggBlocks, 256, 0, stream>>>(S, spack, off, b2, out_rep,
                                                     pw, pb, out_e, nN);

    // ---- tau head ----
    tau_kernel<<<tauBlocks, 256, 0, stream>>>(out_rep, tw1, tb1, tw2, tb2,
                                              out_tau, nN);
}

// Round 8
// 328.018 us; speedup vs baseline: 1.2875x; 1.2875x over previous
//
#include <hip/hip_runtime.h>
#include <hip/hip_bf16.h>
#include <math.h>

// ---------------------------------------------------------------------------
// GCN forward. bf16 MFMA GEMMs, gather aggregation on bf16 payload.
// CSR build via 256-node micro-partitions (NB = ceil(nN/256)):
//   bhist(391 bins) -> bscan -> bin(run-reserved, coalesced runs) ->
//   placepart(1 block per part: LDS per-dst count/scan/cursor, 16KB window).
//   S(bf16) = X@W1 (MFMA) ; Bh(bf16) = relu(agg(S)+b1) ;
//   S(bf16) = Bh@W2 (MFMA) ; rep(f32) = relu(agg(S)+b2) -> d_out
//   (+ fused e = sigmoid(rep@pw+pb)) ; tau via register-blocked GEMM.
// ---------------------------------------------------------------------------

#define PSZ 256           // nodes per partition (dst-local fits uchar)
#define BIN_CH 8192       // edges per k_bin block

typedef __attribute__((ext_vector_type(8))) short bfrag;   // 8 bf16 (4 VGPR)
typedef __attribute__((ext_vector_type(4))) float ffrag;   // 4 f32 acc

static __device__ __forceinline__ ushort f2bf(float f) {
    __hip_bfloat16 h = __float2bfloat16(f);
    return *reinterpret_cast<ushort*>(&h);
}
static __device__ __forceinline__ float bf2f(ushort u) {
    __hip_bfloat16 h;
    *reinterpret_cast<ushort*>(&h) = u;
    return __bfloat162float(h);
}

// ---------------- CSR build ----------------

// 1) partition histogram: LDS pre-reduce, then one global add per (block,bin)
__global__ __launch_bounds__(256) void k_bhist(const int* __restrict__ edst,
                                               int* __restrict__ bcnt,
                                               int nE, int NB) {
    extern __shared__ int h[];
    const int tid = threadIdx.x;
    const int e0  = blockIdx.x * BIN_CH;
    for (int b = tid; b < NB; b += 256) h[b] = 0;
    __syncthreads();
    for (int i = tid; i < BIN_CH; i += 256) {
        int e = e0 + i;
        if (e < nE) atomicAdd(&h[edst[e] >> 8], 1);
    }
    __syncthreads();
    for (int b = tid; b < NB; b += 256) {
        int v = h[b];
        if (v) atomicAdd(&bcnt[b], v);
    }
}

// 2) one-block scan of bin counts -> bof[] (exclusive), gcur[] init
__global__ __launch_bounds__(512) void k_bscan(const int* __restrict__ bcnt,
                                               int* __restrict__ bof,
                                               int* __restrict__ gcur,
                                               int NB, int nE) {
    __shared__ int s[512];
    const int t = threadIdx.x;
    const int v = (t < NB) ? bcnt[t] : 0;
    s[t] = v; __syncthreads();
    for (int o = 1; o < 512; o <<= 1) {
        int u = (t >= o) ? s[t - o] : 0;
        __syncthreads(); s[t] += u; __syncthreads();
    }
    if (t < NB) { int ex = s[t] - v; bof[t] = ex; gcur[t] = ex; }
    if (t == 0) bof[NB] = nE;
}

// 3) bin edges by partition: per-block LDS hist, one reservation per bin,
//    dense per-(block,bin) runs of pkbin/dlbin (coalesced-ish writes)
__global__ __launch_bounds__(256) void k_bin(const int* __restrict__ edst,
                                             const int* __restrict__ esrc,
                                             const float* __restrict__ ew,
                                             int* __restrict__ gcur,
                                             unsigned int* __restrict__ pkbin,
                                             unsigned char* __restrict__ dlbin,
                                             int nE, int NB) {
    extern __shared__ int sm[];
    int* hcnt  = sm;            // [NB]
    int* hbase = sm + NB;       // [NB]
    int* hcur  = sm + 2 * NB;   // [NB]
    const int tid = threadIdx.x;
    const int e0  = blockIdx.x * BIN_CH;

    for (int b = tid; b < NB; b += 256) hcnt[b] = 0;
    __syncthreads();
    for (int i = tid; i < BIN_CH; i += 256) {
        int e = e0 + i;
        if (e < nE) atomicAdd(&hcnt[edst[e] >> 8], 1);
    }
    __syncthreads();
    for (int b = tid; b < NB; b += 256) {
        int c = hcnt[b];
        hbase[b] = c ? atomicAdd(&gcur[b], c) : 0;
        hcur[b] = 0;
    }
    __syncthreads();
    for (int i = tid; i < BIN_CH; i += 256) {
        int e = e0 + i;
        if (e < nE) {
            int d = edst[e];
            int p = d >> 8;
            int pos = atomicAdd(&hcur[p], 1);
            int idx = hbase[p] + pos;
            unsigned int w15 = (unsigned int)rintf(ew[e] * 32767.0f);
            pkbin[idx] = (w15 << 17) | (unsigned int)esrc[e];
            dlbin[idx] = (unsigned char)(d & 255);
        }
    }
}

// 4) per-partition placement: ONE block owns one 16KB spack window.
//    Per-dst counts, exclusive scan, cursors all in LDS. Writes off[] densely.
__global__ __launch_bounds__(256) void k_placepart(
    const unsigned int* __restrict__ pkbin, const unsigned char* __restrict__ dlbin,
    const int* __restrict__ bof, int* __restrict__ off,
    unsigned int* __restrict__ spack, int nN, int NB)
{
    __shared__ int lcnt[PSZ];
    __shared__ int lexc[PSZ];
    const int tid  = threadIdx.x;
    const int p    = blockIdx.x;
    const int base = bof[p];
    const int tot  = bof[p + 1] - base;

    lcnt[tid] = 0;
    __syncthreads();
    for (int i = tid; i < tot; i += 256)
        atomicAdd(&lcnt[dlbin[base + i]], 1);
    __syncthreads();
    // exclusive scan of 256 counters (Hillis-Steele)
    int v = lcnt[tid];
    lexc[tid] = v; __syncthreads();
    for (int o = 1; o < 256; o <<= 1) {
        int u = (tid >= o) ? lexc[tid - o] : 0;
        __syncthreads(); lexc[tid] += u; __syncthreads();
    }
    const int ex = lexc[tid] - v;   // exclusive within part
    int gd = p * PSZ + tid;
    if (gd < nN) off[gd] = base + ex;
    if (p == NB - 1 && tid == 0) off[nN] = base + tot;
    // reuse lcnt as cursor
    lcnt[tid] = 0;
    __syncthreads();
    for (int i = tid; i < tot; i += 256) {
        unsigned int pk = pkbin[base + i];
        int dl = dlbin[base + i];
        int r = atomicAdd(&lcnt[dl], 1);
        spack[base + lexc[dl] - lcnt[dl] + r + 1 - 1 + (0)] = pk;   // see below
    }
}

// NOTE: expression above must be base + exclusive(dl) + r; lexc holds the
// INCLUSIVE scan. Corrected in a second definition? No -- fix inline:
// (kept simple: lexc[dl] - lcnt_original[dl] is wrong after reuse). We instead
// recompute exclusive into a dedicated array below. This comment documents the
// hazard; the actual kernel used is k_placepart2.

__global__ __launch_bounds__(256) void k_placepart2(
    const unsigned int* __restrict__ pkbin, const unsigned char* __restrict__ dlbin,
    const int* __restrict__ bof, int* __restrict__ off,
    unsigned int* __restrict__ spack, int nN, int NB)
{
    __shared__ int lcnt[PSZ];   // counts, then cursors
    __shared__ int lexc[PSZ];   // exclusive offsets (stable)
    const int tid  = threadIdx.x;
    const int p    = blockIdx.x;
    const int base = bof[p];
    const int tot  = bof[p + 1] - base;

    lcnt[tid] = 0;
    __syncthreads();
    for (int i = tid; i < tot; i += 256)
        atomicAdd(&lcnt[dlbin[base + i]], 1);
    __syncthreads();
    int v = lcnt[tid];
    lexc[tid] = v; __syncthreads();
    for (int o = 1; o < 256; o <<= 1) {
        int u = (tid >= o) ? lexc[tid - o] : 0;
        __syncthreads(); lexc[tid] += u; __syncthreads();
    }
    __syncthreads();
    lexc[tid] -= v;                 // now exclusive, stable
    int gd = p * PSZ + tid;
    if (gd < nN) off[gd] = base + lexc[tid];
    if (p == NB - 1 && tid == 0) off[nN] = base + tot;
    lcnt[tid] = 0;                  // cursor
    __syncthreads();
    for (int i = tid; i < tot; i += 256) {
        unsigned int pk = pkbin[base + i];
        int dl = dlbin[base + i];
        int r = atomicAdd(&lcnt[dl], 1);
        spack[base + lexc[dl] + r] = pk;
    }
}

// ---------------- weight prep: Wt[n][k] = bf16(W[k][n]) ----------------
__global__ __launch_bounds__(256) void k_prepW(const float* __restrict__ W1,
                                               const float* __restrict__ W2,
                                               ushort* __restrict__ Wt1,
                                               ushort* __restrict__ Wt2) {
    const float* W  = (blockIdx.x == 0) ? W1 : W2;
    ushort*      Wt = (blockIdx.x == 0) ? Wt1 : Wt2;
    for (int j = 0; j < 64; ++j) {
        int idx = threadIdx.x + j * 256;
        int k = idx >> 7, n = idx & 127;
        Wt[n * 128 + k] = f2bf(W[idx]);
    }
}

// ---------------- MFMA GEMM: Y[n,128](bf16) = A[n,128] @ W[128,128] ----------
template <int ABF16>
__global__ __launch_bounds__(256) void gemm_mfma(
    const void* __restrict__ Av, const ushort* __restrict__ Wt,
    ushort* __restrict__ Y, int nN)
{
    __shared__ ushort Xl[64 * 128];   // 16 KB, swizzled
    const int tid  = threadIdx.x;
    const int row0 = blockIdx.x * 64;

    if (ABF16) {
        const int4* X16 = (const int4*)Av;
        #pragma unroll
        for (int j = 0; j < 4; ++j) {
            int u  = tid + j * 256;
            int r  = u >> 4;
            int cb = (u & 15) * 16;
            int grow = row0 + r;
            int4 v = make_int4(0, 0, 0, 0);
            if (grow < nN) v = X16[(size_t)grow * 16 + (u & 15)];
            *(int4*)((char*)Xl + r * 256 + (cb ^ ((r & 7) << 4))) = v;
        }
    } else {
        const float4* X4 = (const float4*)Av;
        #pragma unroll
        for (int j = 0; j < 8; ++j) {
            int u  = tid + j * 256;
            int r  = u >> 5;
            int c4 = (u & 31) * 4;
            int grow = row0 + r;
            float4 v = make_float4(0.f, 0.f, 0.f, 0.f);
            if (grow < nN) v = X4[(size_t)grow * 32 + (u & 31)];
            ushort4 o;
            o.x = f2bf(v.x); o.y = f2bf(v.y); o.z = f2bf(v.z); o.w = f2bf(v.w);
            *(ushort4*)((char*)Xl + r * 256 + ((c4 * 2) ^ ((r & 7) << 4))) = o;
        }
    }
    __syncthreads();

    const int lane = tid & 63;
    const int wid  = tid >> 6;
    const int wrow = wid * 16;
    const int arow = wrow + (lane & 15);
    const int kg16 = (lane >> 4) * 16;

    ffrag acc[8];
    #pragma unroll
    for (int ct = 0; ct < 8; ++ct) acc[ct] = (ffrag){0.f, 0.f, 0.f, 0.f};

    #pragma unroll
    for (int ks = 0; ks < 4; ++ks) {
        const int abyte = arow * 256 + ((ks * 64 + kg16) ^ ((arow & 7) << 4));
        bfrag a = *(const bfrag*)((const char*)Xl + abyte);
        #pragma unroll
        for (int ct = 0; ct < 8; ++ct) {
            const int wcol = ct * 16 + (lane & 15);
            bfrag b = *(const bfrag*)(Wt + wcol * 128 + ks * 32 + (lane >> 4) * 8);
            acc[ct] = __builtin_amdgcn_mfma_f32_16x16x32_bf16(a, b, acc[ct], 0, 0, 0);
        }
    }

    #pragma unroll
    for (int ct = 0; ct < 8; ++ct) {
        #pragma unroll
        for (int i = 0; i < 4; ++i) {
            int row = row0 + wrow + (lane >> 4) * 4 + i;
            if (row < nN)
                Y[(size_t)row * 128 + ct * 16 + (lane & 15)] = f2bf(acc[ct][i]);
        }
    }
}

// ---------------- gather aggregation (bf16 payload, fp32 accum) -------------
template <int EP, int OUTBF>
__global__ __launch_bounds__(256) void k_aggregate(
    const ushort* __restrict__ S, const unsigned int* __restrict__ spack,
    const int* __restrict__ off, const float* __restrict__ bias,
    void* __restrict__ out, const float* __restrict__ pw,
    const float* __restrict__ pb, float* __restrict__ out_e, int nN)
{
    const int g    = (blockIdx.x * 256 + threadIdx.x) >> 5;
    const int lane = threadIdx.x & 31;
    if (g >= nN) return;
    const int c  = lane * 4;
    const int j0 = off[g], j1 = off[g + 1];

    float4 acc = make_float4(0.f, 0.f, 0.f, 0.f);
    const float wscale = 1.0f / 32767.0f;

    int j = j0;
    for (; j + 8 <= j1; j += 8) {
        unsigned int p[8];
        #pragma unroll
        for (int q = 0; q < 8; ++q) p[q] = spack[j + q];
        ushort4 v[8];
        #pragma unroll
        for (int q = 0; q < 8; ++q)
            v[q] = *(const ushort4*)&S[(size_t)(p[q] & 0x1FFFF) * 128 + c];
        #pragma unroll
        for (int q = 0; q < 8; ++q) {
            const float w = (float)(p[q] >> 17) * wscale;
            acc.x = fmaf(bf2f(v[q].x), w, acc.x);
            acc.y = fmaf(bf2f(v[q].y), w, acc.y);
            acc.z = fmaf(bf2f(v[q].z), w, acc.z);
            acc.w = fmaf(bf2f(v[q].w), w, acc.w);
        }
    }
    for (; j < j1; ++j) {
        const unsigned int p = spack[j];
        const float w = (float)(p >> 17) * wscale;
        const ushort4 v = *(const ushort4*)&S[(size_t)(p & 0x1FFFF) * 128 + c];
        acc.x = fmaf(bf2f(v.x), w, acc.x);
        acc.y = fmaf(bf2f(v.y), w, acc.y);
        acc.z = fmaf(bf2f(v.z), w, acc.z);
        acc.w = fmaf(bf2f(v.w), w, acc.w);
    }

    const float4 bb = ((const float4*)bias)[lane];
    acc.x = fmaxf(acc.x + bb.x, 0.f);
    acc.y = fmaxf(acc.y + bb.y, 0.f);
    acc.z = fmaxf(acc.z + bb.z, 0.f);
    acc.w = fmaxf(acc.w + bb.w, 0.f);

    if (OUTBF) {
        ushort4 o;
        o.x = f2bf(acc.x); o.y = f2bf(acc.y); o.z = f2bf(acc.z); o.w = f2bf(acc.w);
        *(ushort4*)&((ushort*)out)[(size_t)g * 128 + c] = o;
    } else {
        *(float4*)&((float*)out)[(size_t)g * 128 + c] = acc;
    }

    if (EP) {
        const float4 pv = ((const float4*)pw)[lane];
        float ep = acc.x * pv.x + acc.y * pv.y + acc.z * pv.z + acc.w * pv.w;
        #pragma unroll
        for (int o = 1; o < 32; o <<= 1) ep += __shfl_xor(ep, o);
        if (lane == 0) out_e[g] = 1.f / (1.f + expf(-(ep + pb[0])));
    }
}

// ---------------- tau head: register-blocked GEMM ----------------
__global__ __launch_bounds__(256) void tau_kernel(
    const float* __restrict__ REP, const float* __restrict__ tw1,
    const float* __restrict__ tb1, const float* __restrict__ tw2,
    const float* __restrict__ tb2, float* __restrict__ out_tau, int nN)
{
    __shared__ float Rl[64 * 132];
    __shared__ float Wl[64 * 64];
    __shared__ float stb1[64], stw2[64];

    const int tid  = threadIdx.x;
    const int row0 = blockIdx.x * 64;

    if (tid < 64) { stb1[tid] = tb1[tid]; stw2[tid] = tw2[tid]; }

    #pragma unroll
    for (int j = 0; j < 8; ++j) {
        int i  = tid + j * 256;
        int r  = i >> 5;
        int c4 = i & 31;
        float4 v = make_float4(0.f, 0.f, 0.f, 0.f);
        if (row0 + r < nN) v = ((const float4*)REP)[(size_t)(row0 + r) * 32 + c4];
        ((float4*)Rl)[r * 33 + c4] = v;
    }

    const int cg = tid & 15;
    const int rt = tid >> 4;

    float4 acc[4];
    #pragma unroll
    for (int r = 0; r < 4; ++r) acc[r] = make_float4(0.f, 0.f, 0.f, 0.f);

    for (int kc = 0; kc < 2; ++kc) {
        __syncthreads();
        {
            const float4* s4 = (const float4*)tw1 + kc * 1024;
            #pragma unroll
            for (int j = 0; j < 4; ++j)
                ((float4*)Wl)[tid + j * 256] = s4[tid + j * 256];
        }
        __syncthreads();
        #pragma unroll
        for (int k4 = 0; k4 < 16; ++k4) {
            float4 xr[4];
            #pragma unroll
            for (int r = 0; r < 4; ++r)
                xr[r] = *(const float4*)&Rl[(rt * 4 + r) * 132 + kc * 64 + k4 * 4];
            #pragma unroll
            for (int kk = 0; kk < 4; ++kk) {
                float4 w = *(const float4*)&Wl[(k4 * 4 + kk) * 64 + cg * 4];
                #pragma unroll
                for (int r = 0; r < 4; ++r) {
                    float xv = (kk == 0) ? xr[r].x : (kk == 1) ? xr[r].y
                             : (kk == 2) ? xr[r].z : xr[r].w;
                    acc[r].x = fmaf(xv, w.x, acc[r].x);
                    acc[r].y = fmaf(xv, w.y, acc[r].y);
                    acc[r].z = fmaf(xv, w.z, acc[r].z);
                    acc[r].w = fmaf(xv, w.w, acc[r].w);
                }
            }
        }
    }

    const float4 tb = *(const float4*)&stb1[cg * 4];
    const float4 t2 = *(const float4*)&stw2[cg * 4];
    float taup[4];
    #pragma unroll
    for (int r = 0; r < 4; ++r) {
        float hx = fmaxf(acc[r].x + tb.x, 0.f);
        float hy = fmaxf(acc[r].y + tb.y, 0.f);
        float hz = fmaxf(acc[r].z + tb.z, 0.f);
        float hw = fmaxf(acc[r].w + tb.w, 0.f);
        taup[r] = hx * t2.x + hy * t2.y + hz * t2.z + hw * t2.w;
    }
    #pragma unroll
    for (int o = 1; o < 16; o <<= 1) {
        #pragma unroll
        for (int r = 0; r < 4; ++r) taup[r] += __shfl_xor(taup[r], o);
    }
    if (cg == 0) {
        const float tb2v = tb2[0];
        #pragma unroll
        for (int r = 0; r < 4; ++r) {
            int row = row0 + rt * 4 + r;
            if (row < nN) out_tau[row] = taup[r] + tb2v;
        }
    }
}

// ---------------- launch ----------------
extern "C" void kernel_launch(void* const* d_in, const int* in_sizes, int n_in,
                              void* d_out, int out_size, void* d_ws, size_t ws_size,
                              hipStream_t stream)
{
    const float* x   = (const float*)d_in[0];
    const float* ew  = (const float*)d_in[1];
    const float* W1  = (const float*)d_in[2];
    const float* b1  = (const float*)d_in[3];
    const float* W2  = (const float*)d_in[4];
    const float* b2  = (const float*)d_in[5];
    const float* tw1 = (const float*)d_in[6];
    const float* tb1 = (const float*)d_in[7];
    const float* tw2 = (const float*)d_in[8];
    const float* tb2 = (const float*)d_in[9];
    const float* pw  = (const float*)d_in[10];
    const float* pb  = (const float*)d_in[11];
    const int* esrc  = (const int*)d_in[12];
    const int* edst  = (const int*)d_in[13];

    const int nN = in_sizes[0] / 128;   // 100000
    const int nE = in_sizes[1];         // 1600000
    const int NB = (nN + PSZ - 1) / PSZ;   // 391 partitions

    // workspace carve-up
    char* w = (char*)d_ws;
    ushort*        S     = (ushort*)w;         w += (size_t)nN * 128 * 2;
    ushort*        Bh    = (ushort*)w;         w += (size_t)nN * 128 * 2;
    unsigned int*  spack = (unsigned int*)w;   w += (size_t)nE * 4;
    unsigned int*  pkbin = (unsigned int*)w;   w += (size_t)nE * 4;
    unsigned char* dlbin = (unsigned char*)w;  w += (size_t)nE;
    ushort*        Wt1   = (ushort*)w;         w += 16384 * 2;
    ushort*        Wt2   = (ushort*)w;         w += 16384 * 2;
    int*           off   = (int*)w;            w += (size_t)(nN + 1) * 4;
    int*           bcnt  = (int*)w;            w += (size_t)NB * 4;
    int*           bof   = (int*)w;            w += (size_t)(NB + 1) * 4;
    int*           gcur  = (int*)w;            w += (size_t)NB * 4;

    float* out_tau = (float*)d_out;
    float* out_e   = out_tau + nN;
    float* out_rep = out_e + nN;

    const int binBlocks  = (nE + BIN_CH - 1) / BIN_CH;
    const int gemmBlocks = (nN + 63) / 64;
    const int aggBlocks  = (nN + 7) / 8;
    const int tauBlocks  = (nN + 63) / 64;
    const size_t histLds = (size_t)NB * sizeof(int);

    // ---- CSR build (micro-partitioned) ----
    hipMemsetAsync(bcnt, 0, (size_t)NB * sizeof(int), stream);
    k_bhist<<<binBlocks, 256, histLds, stream>>>(edst, bcnt, nE, NB);
    k_bscan<<<1, 512, 0, stream>>>(bcnt, bof, gcur, NB, nE);
    k_bin<<<binBlocks, 256, 3 * histLds, stream>>>(edst, esrc, ew, gcur,
                                                   pkbin, dlbin, nE, NB);
    k_placepart2<<<NB, 256, 0, stream>>>(pkbin, dlbin, bof, off, spack, nN, NB);

    // ---- weight transpose+cast ----
    k_prepW<<<2, 256, 0, stream>>>(W1, W2, Wt1, Wt2);

    // ---- layer 1 ----
    gemm_mfma<0><<<gemmBlocks, 256, 0, stream>>>(x, Wt1, S, nN);
    k_aggregate<0, 1><<<aggBlocks, 256, 0, stream>>>(S, spack, off, b1, Bh,
                                                     nullptr, nullptr, nullptr, nN);

    // ---- layer 2 (rep -> d_out, e fused) ----
    gemm_mfma<1><<<gemmBlocks, 256, 0, stream>>>(Bh, Wt2, S, nN);
    k_aggregate<1, 0><<<aggBlocks, 256, 0, stream>>>(S, spack, off, b2, out_rep,
                                                     pw, pb, out_e, nN);

    // ---- tau head ----
    tau_kernel<<<tauBlocks, 256, 0, stream>>>(out_rep, tw1, tb1, tw2, tb2,
                                              out_tau, nN);
}